// Round 7
// baseline (259.737 us; speedup 1.0000x reference)
//
#include <hip/hip_runtime.h>
#include <math.h>

#define EMBED 128
#define LDSPAD 136   // 128 + 8 bf16 pad -> 272 B row stride
#define DBINS 64     // degree bins for counting sort (deg clamped to 63)

#define TWO_LOG2E 2.8853900817779268f
#define DEFER_THR 32.0f

typedef __attribute__((ext_vector_type(8))) short short8;
typedef __attribute__((ext_vector_type(4))) float floatx4;

__device__ __forceinline__ float ex2(float x) { return __builtin_amdgcn_exp2f(x); }

__device__ __forceinline__ float fast_tanh2(float x) {     // 1 mul + 1 exp + 1 rcp
    float e = ex2(TWO_LOG2E * x);                           // x<<0 -> 0 -> -1; x>>0 -> inf -> 1
    return 1.0f - 2.0f * __builtin_amdgcn_rcpf(1.0f + e);
}

__device__ __forceinline__ unsigned short f2b(float f) {   // fp32 -> bf16 RNE
    union { float f; unsigned int u; } v; v.f = f;
    unsigned int r = v.u + 0x7FFFu + ((v.u >> 16) & 1u);
    return (unsigned short)(r >> 16);
}

__device__ __forceinline__ float b2f(short u) {
    union { float f; unsigned int i; } v;
    v.i = ((unsigned int)(unsigned short)u) << 16;
    return v.f;
}

// sum over the 16-lane DPP row via sum-of-rotations (exact allreduce)
template <int CTRL>
__device__ __forceinline__ float dpp_add_f(float x) {
    int y = __builtin_amdgcn_update_dpp(0, __float_as_int(x), CTRL, 0xF, 0xF, false);
    return x + __int_as_float(y);
}
__device__ __forceinline__ float dpp_sum16(float s) {
    s = dpp_add_f<0x121>(s);   // row_ror:1
    s = dpp_add_f<0x122>(s);   // row_ror:2
    s = dpp_add_f<0x124>(s);   // row_ror:4
    s = dpp_add_f<0x128>(s);   // row_ror:8
    return s;
}

// ---------------- K0: cast ent/rel/W to bf16 + head histogram (+ zero ghist) ----------------
__global__ __launch_bounds__(256) void k_cast_hist(
    const float* __restrict__ ent, const float* __restrict__ rel, const float* __restrict__ W,
    short* __restrict__ entb, short* __restrict__ relb, short* __restrict__ wb,
    const int* __restrict__ heads, int* __restrict__ cnt, int* __restrict__ ghist,
    int ngE, int ngR, int ngW, int E)
{
    if (blockIdx.x == 0 && threadIdx.x < DBINS) ghist[threadIdx.x] = 0;  // no reader until k_scan1
    int stride = gridDim.x * 256;
    int total = ngE + ngR + ngW;
    for (int g = blockIdx.x * 256 + threadIdx.x; g < total; g += stride) {
        const float4* src; short* dst;
        if (g < ngE)            { src = (const float4*)ent + (size_t)g * 2;              dst = entb + (size_t)g * 8; }
        else if (g < ngE + ngR) { int g2 = g - ngE;       src = (const float4*)rel + (size_t)g2 * 2; dst = relb + (size_t)g2 * 8; }
        else                    { int g2 = g - ngE - ngR; src = (const float4*)W   + (size_t)g2 * 2; dst = wb   + (size_t)g2 * 8; }
        float4 a = src[0], b = src[1];
        short8 o;
        o[0] = (short)f2b(a.x); o[1] = (short)f2b(a.y); o[2] = (short)f2b(a.z); o[3] = (short)f2b(a.w);
        o[4] = (short)f2b(b.x); o[5] = (short)f2b(b.y); o[6] = (short)f2b(b.z); o[7] = (short)f2b(b.w);
        *(short8*)dst = o;
    }
    for (int e = blockIdx.x * 256 + threadIdx.x; e < E; e += stride)
        atomicAdd(cnt + heads[e], 1);
}

// ---------------- K1a: block scan of cnt + degree histogram ----------------
__global__ __launch_bounds__(1024) void k_scan1(
    const int* __restrict__ cnt, int* __restrict__ offs,
    int* __restrict__ bsum, int* __restrict__ ghist, int N)
{
    __shared__ int wsum[16];
    __shared__ int dh[DBINS];
    const int tid = threadIdx.x;
    if (tid < DBINS) dh[tid] = 0;
    int i = blockIdx.x * 1024 + tid;
    int v = (i < N) ? cnt[i] : 0;
    __syncthreads();
    if (i < N) atomicAdd(&dh[v < DBINS ? v : DBINS - 1], 1);
    int x = v;
    #pragma unroll
    for (int d = 1; d < 64; d <<= 1) {
        int y = __shfl_up(x, d, 64);
        if ((tid & 63) >= d) x += y;
    }
    if ((tid & 63) == 63) wsum[tid >> 6] = x;
    __syncthreads();
    if (tid < 16) {
        int w = wsum[tid];
        #pragma unroll
        for (int d = 1; d < 16; d <<= 1) {
            int y = __shfl_up(w, d, 16);
            if (tid >= d) w += y;
        }
        wsum[tid] = w;
    }
    __syncthreads();
    int add = (tid >= 64) ? wsum[(tid >> 6) - 1] : 0;
    int incl = x + add;
    if (i < N) offs[i] = incl - v;
    if (tid == 1023) bsum[blockIdx.x] = incl;
    if (tid < DBINS && dh[tid] > 0) atomicAdd(ghist + tid, dh[tid]);
}

// ---------------- K1b: finalize offs/cursor + counting-sort scatter (scan2 folded in) ----------------
__global__ __launch_bounds__(256) void k_scan23(
    int* __restrict__ offs, const int* __restrict__ bsum,
    int* __restrict__ cursor, const int* __restrict__ cnt,
    const int* __restrict__ ghist, int* __restrict__ bincur,
    int* __restrict__ order, int N, int nb)
{
    __shared__ int sb[256];      // exclusive-scanned bsum
    __shared__ int ws4[4];
    __shared__ int dbs[DBINS];   // exclusive-scanned ghist
    __shared__ int lcnt[DBINS];
    __shared__ int lbase[DBINS];
    const int tid = threadIdx.x;

    int v = (tid < nb) ? bsum[tid] : 0;
    int x = v;
    #pragma unroll
    for (int d = 1; d < 64; d <<= 1) {
        int y = __shfl_up(x, d, 64);
        if ((tid & 63) >= d) x += y;
    }
    if ((tid & 63) == 63) ws4[tid >> 6] = x;
    __syncthreads();
    if (tid < 4) {
        int w = ws4[tid];
        #pragma unroll
        for (int d = 1; d < 4; d <<= 1) {
            int y = __shfl_up(w, d, 4);
            if (tid >= d) w += y;
        }
        ws4[tid] = w;
    }
    __syncthreads();
    int add = (tid >= 64) ? ws4[(tid >> 6) - 1] : 0;
    sb[tid] = x + add - v;            // exclusive prefix of bsum

    if (tid < 64) {                   // ghist exclusive scan (one wave)
        int g = ghist[tid];
        int s = g;
        #pragma unroll
        for (int d = 1; d < 64; d <<= 1) {
            int y = __shfl_up(s, d, 64);
            if (tid >= d) s += y;
        }
        dbs[tid] = s - g;
    }
    if (tid < DBINS) lcnt[tid] = 0;
    __syncthreads();

    int i = blockIdx.x * 256 + tid;
    int deg = 0, lrank = 0;
    if (i < N) {
        int o = offs[i] + sb[i >> 10];
        offs[i] = o;
        cursor[i] = o;
        int c = cnt[i];
        deg = c < DBINS ? c : DBINS - 1;
        lrank = atomicAdd(&lcnt[deg], 1);          // local rank within block
    }
    __syncthreads();
    if (tid < DBINS) {
        int n = lcnt[tid];
        lbase[tid] = (n > 0) ? (dbs[tid] + atomicAdd(bincur + tid, n)) : 0;
    }
    __syncthreads();
    if (i < N) order[lbase[deg] + lrank] = i;
}

// ---------------- K2: CSR slot-fill: packed (tail, rel) per slot ----------------
__global__ __launch_bounds__(256) void k_csr(
    const int* __restrict__ heads, const int* __restrict__ rels,
    const int* __restrict__ tails, int* __restrict__ cursor,
    int2* __restrict__ tr, int E)
{
    int e = blockIdx.x * 256 + threadIdx.x;
    if (e >= E) return;
    int pos = atomicAdd(cursor + heads[e], 1);
    tr[pos] = make_int2(tails[e], rels[e]);
}

// ---------------- K3: fused score + online-softmax aggregate ----------------
// 16 lanes per head; descending degree order (LPT). Flat edge loop: (t,r)
// read directly per-j from the L1-hot tr line (same addr across the 16-lane
// group -> broadcast) instead of shfl broadcasts -- removes 2 bpermutes and
// all chunk logic from the critical path. Depth-2 tr prefetch, depth-1 row
// prefetch. j-body math identical to the verified r5/r6 body.
// Global max via guarded device atomicMax on ordered-uint key (replaces
// blockmax[] + k_maxred kernel).
__global__ __launch_bounds__(256) void k_fused(
    const short* __restrict__ entb, const short* __restrict__ relb,
    const int* __restrict__ offs, const int* __restrict__ cnt,
    const int2* __restrict__ tr, const int* __restrict__ order,
    short* __restrict__ accb, float* __restrict__ mh, float* __restrict__ lh,
    unsigned int* __restrict__ Mbits, int N)
{
    const int tid = threadIdx.x;
    const int lane = tid & 15;
    int head0 = blockIdx.x * 16 + (tid >> 4);
    int head  = (head0 < N) ? order[(N - 1) - head0] : N;   // reverse = descending degree
    float mt = -INFINITY;              // true max (for global M)
    if (head < N) {
        int start = offs[head];
        int c     = cnt[head];
        short8 hh = *((const short8*)(entb + (size_t)head * EMBED) + lane);
        float hf[8];
        #pragma unroll
        for (int i = 0; i < 8; ++i) hf[i] = b2f(hh[i]);
        float m = -INFINITY;           // deferred reference point
        float l = 0.f;
        float acc[8] = {0,0,0,0,0,0,0,0};
        if (c > 0) {
            int2 tc = tr[start];
            short8 vtc = *((const short8*)(entb + (size_t)tc.x * EMBED) + lane);
            short8 vrc = *((const short8*)(relb + (size_t)tc.y * EMBED) + lane);
            int2 tn = (c > 1) ? tr[start + 1] : tc;
            for (int j = 0; j < c; ++j) {
                // prefetch rows for j+1 and tr for j+2 (clamped; reloads are L1-hot)
                short8 vtn = *((const short8*)(entb + (size_t)tn.x * EMBED) + lane);
                short8 vrn = *((const short8*)(relb + (size_t)tn.y * EMBED) + lane);
                int j2 = (j + 2 < c) ? j + 2 : c - 1;
                int2 t2 = tr[start + j2];
                float s = 0.f;
                float vtf[8];
                #pragma unroll
                for (int i = 0; i < 8; ++i) {
                    vtf[i] = b2f(vtc[i]);
                    s = fmaf(vtf[i], fast_tanh2(hf[i] + b2f(vrc[i])), s);
                }
                s = dpp_sum16(s);
                mt = fmaxf(mt, s);
                float dlt = s - m;                 // first edge: +inf
                if (dlt > DEFER_THR) {             // rare after j=0 (j=0 synchronized)
                    float alpha = __expf(-dlt);    // exp(m - s); -inf -> 0
                    l *= alpha;
                    #pragma unroll
                    for (int q = 0; q < 8; ++q) acc[q] *= alpha;
                    m = s;
                    dlt = 0.f;
                }
                float p = __expf(dlt);             // p <= e^32: fp32-safe
                l += p;
                #pragma unroll
                for (int q = 0; q < 8; ++q)
                    acc[q] = fmaf(p, vtf[q], acc[q]);
                vtc = vtn;
                vrc = vrn;
                tn  = t2;
            }
        }
        short8 o;
        #pragma unroll
        for (int q = 0; q < 8; ++q) o[q] = (short)f2b(acc[q]);
        *((short8*)(accb + (size_t)head * EMBED) + lane) = o;
        if (lane == 0) { mh[head] = m; lh[head] = l; }
    }
    // block max -> single guarded device atomicMax (ordered-uint key)
    __shared__ float wmax[4];
    float wm = mt;
    #pragma unroll
    for (int off = 1; off < 64; off <<= 1) wm = fmaxf(wm, __shfl_xor(wm, off, 64));
    if ((tid & 63) == 0) wmax[tid >> 6] = wm;
    __syncthreads();
    if (tid == 0) {
        float bm = fmaxf(fmaxf(wmax[0], wmax[1]), fmaxf(wmax[2], wmax[3]));
        unsigned int u = __float_as_uint(bm);
        unsigned int key = (u & 0x80000000u) ? ~u : (u | 0x80000000u);
        if (key > *((volatile unsigned int*)Mbits))   // stale-read guard: skip most atomics
            atomicMax(Mbits, key);
    }
}

// ---------------- K4: fused normalize + x = ent + agg + bf16 MFMA GEMM ----------------
// B-fragments read straight from wb (32 KB, L2-resident; each 64B line fully
// consumed by a quad) -- no ws LDS tile, half the LDS, 4 blocks/CU.
__global__ __launch_bounds__(256) void k_gemm_f(
    const short* __restrict__ entb, const short* __restrict__ accb,
    const float* __restrict__ mh, const float* __restrict__ lh,
    const unsigned int* __restrict__ Mbits, const short* __restrict__ wb,
    float* __restrict__ out, int N)
{
    __shared__ short xs[128 * LDSPAD];
    __shared__ float invs[128];
    const int tid = threadIdx.x;
    const int n0  = blockIdx.x * 128;
    unsigned int k = Mbits[0];
    const float M = (k & 0x80000000u) ? __uint_as_float(k & 0x7FFFFFFFu)
                                      : __uint_as_float(~k);

    if (tid < 128) {
        int g = n0 + tid;
        invs[tid] = (g < N) ? 1.0f / (lh[g] + 1e-10f * __expf(M - mh[g])) : 0.f;  // inf -> 0
    }
    __syncthreads();
    // stage x = ent + acc*inv: 2048 short8 chunks, 8 per thread
    #pragma unroll
    for (int it = 0; it < 8; ++it) {
        int ch = it * 256 + tid;
        int row = ch >> 4, col8 = ch & 15;
        int g = n0 + row;
        short8 v = {0,0,0,0,0,0,0,0};
        if (g < N) {
            float inv = invs[row];
            short8 e8 = *((const short8*)(entb + (size_t)g * EMBED) + col8);
            short8 a8 = *((const short8*)(accb + (size_t)g * EMBED) + col8);
            #pragma unroll
            for (int q = 0; q < 8; ++q)
                v[q] = (short)f2b(b2f(e8[q]) + b2f(a8[q]) * inv);
        }
        *(short8*)(xs + row * LDSPAD + col8 * 8) = v;
    }
    __syncthreads();

    const int wv   = tid >> 6;
    const int lane = tid & 63;
    const int n16  = lane & 15;
    const int quad = lane >> 4;

    floatx4 acc[2][8];
    #pragma unroll
    for (int rt = 0; rt < 2; ++rt)
        #pragma unroll
        for (int jt = 0; jt < 8; ++jt)
            acc[rt][jt] = (floatx4){0.f, 0.f, 0.f, 0.f};

    #pragma unroll
    for (int kc = 0; kc < 4; ++kc) {
        int koff = kc * 32 + quad * 8;
        short8 a0 = *(const short8*)(xs + (wv * 32      + n16) * LDSPAD + koff);
        short8 a1 = *(const short8*)(xs + (wv * 32 + 16 + n16) * LDSPAD + koff);
        #pragma unroll
        for (int jt = 0; jt < 8; ++jt) {
            short8 b = *(const short8*)(wb + (jt * 16 + n16) * EMBED + koff);
            acc[0][jt] = __builtin_amdgcn_mfma_f32_16x16x32_bf16(a0, b, acc[0][jt], 0, 0, 0);
            acc[1][jt] = __builtin_amdgcn_mfma_f32_16x16x32_bf16(a1, b, acc[1][jt], 0, 0, 0);
        }
    }

    #pragma unroll
    for (int rt = 0; rt < 2; ++rt) {
        int rowbase = n0 + wv * 32 + rt * 16 + quad * 4;
        #pragma unroll
        for (int r = 0; r < 4; ++r) {
            int grow = rowbase + r;
            if (grow < N) {
                float* o = out + (size_t)grow * EMBED + n16;
                #pragma unroll
                for (int jt = 0; jt < 8; ++jt) {
                    float v = acc[rt][jt][r];
                    o[jt * 16] = (v > 0.f) ? v : 0.2f * v;
                }
            }
        }
    }
}

extern "C" void kernel_launch(void* const* d_in, const int* in_sizes, int n_in,
                              void* d_out, int out_size, void* d_ws, size_t ws_size,
                              hipStream_t stream)
{
    const float* ent   = (const float*)d_in[0];   // entity_emb  [N,128] fp32
    const float* rel   = (const float*)d_in[1];   // rel_embed   [R,128] fp32
    const float* W     = (const float*)d_in[2];   // W           [128,128] fp32
    const int*   heads = (const int*)d_in[3];
    const int*   rels  = (const int*)d_in[4];
    const int*   tails = (const int*)d_in[5];
    const int E = in_sizes[3];
    const int N = in_sizes[0] / EMBED;
    const int R = in_sizes[1] / EMBED;
    float* out = (float*)d_out;

    // ws layout:
    // accb[N*128]s | mh[N]f | lh[N]f | tr[E]int2 | cnt[N]i | bincur[64]i | Mbits[4]u |
    // offs[N]i | cursor[N]i | bsum[1024]i | ghist[64]i | order[N]i | wb[16384]s |
    // entb[N*128]s | relb[R*128]s
    short* accb      = (short*)d_ws;
    float* mh        = (float*)(accb + (size_t)N * EMBED);
    float* lh        = mh + N;
    int2*  tr        = (int2*)(lh + N);
    int*   cnt       = (int*)(tr + E);
    int*   bincur    = cnt + N;                     // zeroed with cnt
    unsigned int* Mbits = (unsigned int*)(bincur + DBINS);  // zeroed with cnt (4-int slot)
    int*   offs      = (int*)(Mbits + 4);
    int*   cursor    = offs + N;
    int*   bsum      = cursor + N;
    int*   ghist     = bsum + 1024;
    int*   order     = ghist + DBINS;
    short* wb        = (short*)(order + N);         // 128*128 bf16 = 32 KB
    short* entb      = wb + 16384;
    short* relb      = entb + (size_t)N * EMBED;

    const int nb  = (N + 1023) >> 10;       // scan blocks (<= 256 assumed: N <= 262144)
    const int ngh = (N + 15) / 16;          // per-head group blocks

    hipMemsetAsync(cnt, 0, (size_t)(N + DBINS + 4) * sizeof(int), stream);

    int ngE = N * EMBED / 8, ngR = R * EMBED / 8, ngW = EMBED * EMBED / 8;
    k_cast_hist<<<2048, 256, 0, stream>>>(ent, rel, W, entb, relb, wb, heads, cnt, ghist, ngE, ngR, ngW, E);
    k_scan1<<<nb, 1024, 0, stream>>>(cnt, offs, bsum, ghist, N);
    k_scan23<<<(N + 255) / 256, 256, 0, stream>>>(offs, bsum, cursor, cnt, ghist, bincur, order, N, nb);
    k_csr<<<(E + 255) / 256, 256, 0, stream>>>(heads, rels, tails, cursor, tr, E);
    k_fused<<<ngh, 256, 0, stream>>>(entb, relb, offs, cnt, tr, order, accb, mh, lh, Mbits, N);
    k_gemm_f<<<(N + 127) / 128, 256, 0, stream>>>(entb, accb, mh, lh, Mbits, wb, out, N);
}

// Round 8
// 242.876 us; speedup vs baseline: 1.0694x; 1.0694x over previous
//
#include <hip/hip_runtime.h>
#include <math.h>

#define EMBED 128
#define BMAX 8192    // blockmax array (fused grid = ceil(N/16) = 6250 <= BMAX)
#define LDSPAD 136   // 128 + 8 bf16 pad -> 272 B row stride
#define DBINS 64     // degree bins for counting sort (deg clamped to 63)

#define TWO_LOG2E 2.8853900817779268f
#define DEFER_THR 32.0f

// (tail, rel) packed: tail in bits [0,20), rel in bits [20,32). Requires
// N < 2^20 (here N=100000) and R < 2^12 (here 64).
#define TMASK 0xFFFFF

typedef __attribute__((ext_vector_type(8))) short short8;
typedef __attribute__((ext_vector_type(4))) float floatx4;

__device__ __forceinline__ float ex2(float x) { return __builtin_amdgcn_exp2f(x); }

__device__ __forceinline__ float fast_tanh2(float x) {     // 1 mul + 1 exp + 1 rcp
    float e = ex2(TWO_LOG2E * x);                           // x<<0 -> 0 -> -1; x>>0 -> inf -> 1
    return 1.0f - 2.0f * __builtin_amdgcn_rcpf(1.0f + e);
}

__device__ __forceinline__ unsigned short f2b(float f) {   // fp32 -> bf16 RNE
    union { float f; unsigned int u; } v; v.f = f;
    unsigned int r = v.u + 0x7FFFu + ((v.u >> 16) & 1u);
    return (unsigned short)(r >> 16);
}

__device__ __forceinline__ float b2f(short u) {
    union { float f; unsigned int i; } v;
    v.i = ((unsigned int)(unsigned short)u) << 16;
    return v.f;
}

// sum over the 16-lane DPP row via sum-of-rotations (exact allreduce)
template <int CTRL>
__device__ __forceinline__ float dpp_add_f(float x) {
    int y = __builtin_amdgcn_update_dpp(0, __float_as_int(x), CTRL, 0xF, 0xF, false);
    return x + __int_as_float(y);
}
__device__ __forceinline__ float dpp_sum16(float s) {
    s = dpp_add_f<0x121>(s);   // row_ror:1
    s = dpp_add_f<0x122>(s);   // row_ror:2
    s = dpp_add_f<0x124>(s);   // row_ror:4
    s = dpp_add_f<0x128>(s);   // row_ror:8
    return s;
}

// ---------------- K0: cast ent/rel/W to bf16 + head histogram (+ zero ghist) ----------------
__global__ __launch_bounds__(256) void k_cast_hist(
    const float* __restrict__ ent, const float* __restrict__ rel, const float* __restrict__ W,
    short* __restrict__ entb, short* __restrict__ relb, short* __restrict__ wb,
    const int* __restrict__ heads, int* __restrict__ cnt, int* __restrict__ ghist,
    int ngE, int ngR, int ngW, int E)
{
    if (blockIdx.x == 0 && threadIdx.x < DBINS) ghist[threadIdx.x] = 0;  // no reader until k_scan1
    int stride = gridDim.x * 256;
    int total = ngE + ngR + ngW;
    for (int g = blockIdx.x * 256 + threadIdx.x; g < total; g += stride) {
        const float4* src; short* dst;
        if (g < ngE)            { src = (const float4*)ent + (size_t)g * 2;              dst = entb + (size_t)g * 8; }
        else if (g < ngE + ngR) { int g2 = g - ngE;       src = (const float4*)rel + (size_t)g2 * 2; dst = relb + (size_t)g2 * 8; }
        else                    { int g2 = g - ngE - ngR; src = (const float4*)W   + (size_t)g2 * 2; dst = wb   + (size_t)g2 * 8; }
        float4 a = src[0], b = src[1];
        short8 o;
        o[0] = (short)f2b(a.x); o[1] = (short)f2b(a.y); o[2] = (short)f2b(a.z); o[3] = (short)f2b(a.w);
        o[4] = (short)f2b(b.x); o[5] = (short)f2b(b.y); o[6] = (short)f2b(b.z); o[7] = (short)f2b(b.w);
        *(short8*)dst = o;
    }
    for (int e = blockIdx.x * 256 + threadIdx.x; e < E; e += stride)
        atomicAdd(cnt + heads[e], 1);
}

// ---------------- K1a: block scan of cnt + degree histogram ----------------
__global__ __launch_bounds__(1024) void k_scan1(
    const int* __restrict__ cnt, int* __restrict__ offs,
    int* __restrict__ bsum, int* __restrict__ ghist, int N)
{
    __shared__ int wsum[16];
    __shared__ int dh[DBINS];
    const int tid = threadIdx.x;
    if (tid < DBINS) dh[tid] = 0;
    int i = blockIdx.x * 1024 + tid;
    int v = (i < N) ? cnt[i] : 0;
    __syncthreads();
    if (i < N) atomicAdd(&dh[v < DBINS ? v : DBINS - 1], 1);
    int x = v;
    #pragma unroll
    for (int d = 1; d < 64; d <<= 1) {
        int y = __shfl_up(x, d, 64);
        if ((tid & 63) >= d) x += y;
    }
    if ((tid & 63) == 63) wsum[tid >> 6] = x;
    __syncthreads();
    if (tid < 16) {
        int w = wsum[tid];
        #pragma unroll
        for (int d = 1; d < 16; d <<= 1) {
            int y = __shfl_up(w, d, 16);
            if (tid >= d) w += y;
        }
        wsum[tid] = w;
    }
    __syncthreads();
    int add = (tid >= 64) ? wsum[(tid >> 6) - 1] : 0;
    int incl = x + add;
    if (i < N) offs[i] = incl - v;
    if (tid == 1023) bsum[blockIdx.x] = incl;
    if (tid < DBINS && dh[tid] > 0) atomicAdd(ghist + tid, dh[tid]);
}

// ---------------- K1b: finalize offs/cursor + counting-sort scatter (scan2 folded in) ----------------
__global__ __launch_bounds__(256) void k_scan23(
    int* __restrict__ offs, const int* __restrict__ bsum,
    int* __restrict__ cursor, const int* __restrict__ cnt,
    const int* __restrict__ ghist, int* __restrict__ bincur,
    int* __restrict__ order, int N, int nb)
{
    __shared__ int sb[256];      // exclusive-scanned bsum
    __shared__ int ws4[4];
    __shared__ int dbs[DBINS];   // exclusive-scanned ghist
    __shared__ int lcnt[DBINS];
    __shared__ int lbase[DBINS];
    const int tid = threadIdx.x;

    int v = (tid < nb) ? bsum[tid] : 0;
    int x = v;
    #pragma unroll
    for (int d = 1; d < 64; d <<= 1) {
        int y = __shfl_up(x, d, 64);
        if ((tid & 63) >= d) x += y;
    }
    if ((tid & 63) == 63) ws4[tid >> 6] = x;
    __syncthreads();
    if (tid < 4) {
        int w = ws4[tid];
        #pragma unroll
        for (int d = 1; d < 4; d <<= 1) {
            int y = __shfl_up(w, d, 4);
            if (tid >= d) w += y;
        }
        ws4[tid] = w;
    }
    __syncthreads();
    int add = (tid >= 64) ? ws4[(tid >> 6) - 1] : 0;
    sb[tid] = x + add - v;            // exclusive prefix of bsum

    if (tid < 64) {                   // ghist exclusive scan (one wave)
        int g = ghist[tid];
        int s = g;
        #pragma unroll
        for (int d = 1; d < 64; d <<= 1) {
            int y = __shfl_up(s, d, 64);
            if (tid >= d) s += y;
        }
        dbs[tid] = s - g;
    }
    if (tid < DBINS) lcnt[tid] = 0;
    __syncthreads();

    int i = blockIdx.x * 256 + tid;
    int deg = 0, lrank = 0;
    if (i < N) {
        int o = offs[i] + sb[i >> 10];
        offs[i] = o;
        cursor[i] = o;
        int c = cnt[i];
        deg = c < DBINS ? c : DBINS - 1;
        lrank = atomicAdd(&lcnt[deg], 1);          // local rank within block
    }
    __syncthreads();
    if (tid < DBINS) {
        int n = lcnt[tid];
        lbase[tid] = (n > 0) ? (dbs[tid] + atomicAdd(bincur + tid, n)) : 0;
    }
    __syncthreads();
    if (i < N) order[lbase[deg] + lrank] = i;
}

// ---------------- K2: CSR slot-fill: packed tail|rel<<20 per slot ----------------
__global__ __launch_bounds__(256) void k_csr(
    const int* __restrict__ heads, const int* __restrict__ rels,
    const int* __restrict__ tails, int* __restrict__ cursor,
    int* __restrict__ trp, int E)
{
    int e = blockIdx.x * 256 + threadIdx.x;
    if (e >= E) return;
    int pos = atomicAdd(cursor + heads[e], 1);
    trp[pos] = tails[e] | (rels[e] << 20);
}

// ---------------- K3: fused score + online-softmax aggregate ----------------
// 16 lanes per head; DESCENDING degree order (LPT). Structure identical to
// the verified r6 kernel except (t,r) arrive as ONE packed int -> a single
// shfl broadcast per j (was two).
__global__ __launch_bounds__(256) void k_fused(
    const short* __restrict__ entb, const short* __restrict__ relb,
    const int* __restrict__ offs, const int* __restrict__ cnt,
    const int* __restrict__ trp, const int* __restrict__ order,
    short* __restrict__ accb, float* __restrict__ mh, float* __restrict__ lh,
    float* __restrict__ blockmax, int N, int R)
{
    const int tid = threadIdx.x;
    const int lane = tid & 15;
    int head0 = blockIdx.x * 16 + (tid >> 4);
    int head  = (head0 < N) ? order[(N - 1) - head0] : N;   // reverse = descending degree
    float mt = -INFINITY;              // true max (for global M)
    if (head < N) {
        int start = offs[head];
        int c     = cnt[head];
        short8 hh = *((const short8*)(entb + (size_t)head * EMBED) + lane);
        float hf[8];
        #pragma unroll
        for (int i = 0; i < 8; ++i) hf[i] = b2f(hh[i]);
        float m = -INFINITY;           // deferred reference point
        float l = 0.f;
        float acc[8] = {0,0,0,0,0,0,0,0};
        for (int base = 0; base < c; base += 16) {
            int rem = c - base;
            int mm  = rem < 16 ? rem : 16;
            int trv = 0;
            if (lane < mm) trv = trp[start + base + lane];
            int p0 = __shfl(trv, 0, 16);
            short8 vtc = *((const short8*)(entb + (size_t)(p0 & TMASK) * EMBED) + lane);
            short8 vrc = *((const short8*)(relb + (size_t)(p0 >> 20) * EMBED) + lane);
            for (int j = 0; j < mm; ++j) {
                int jn = (j + 1 < mm) ? j + 1 : j;       // clamp: last iter reloads (L1-hot)
                int pn = __shfl(trv, jn, 16);
                short8 vtn = *((const short8*)(entb + (size_t)(pn & TMASK) * EMBED) + lane);
                short8 vrn = *((const short8*)(relb + (size_t)(pn >> 20) * EMBED) + lane);
                float s = 0.f;
                float vtf[8];
                #pragma unroll
                for (int i = 0; i < 8; ++i) {
                    vtf[i] = b2f(vtc[i]);
                    s = fmaf(vtf[i], fast_tanh2(hf[i] + b2f(vrc[i])), s);
                }
                s = dpp_sum16(s);
                mt = fmaxf(mt, s);
                float dlt = s - m;                 // first edge: +inf
                if (dlt > DEFER_THR) {             // rare after j=0 (j=0 synchronized)
                    float alpha = __expf(-dlt);    // exp(m - s); -inf -> 0
                    l *= alpha;
                    #pragma unroll
                    for (int q = 0; q < 8; ++q) acc[q] *= alpha;
                    m = s;
                    dlt = 0.f;
                }
                float p = __expf(dlt);             // p <= e^32: fp32-safe
                l += p;
                #pragma unroll
                for (int q = 0; q < 8; ++q)
                    acc[q] = fmaf(p, vtf[q], acc[q]);
                vtc = vtn;
                vrc = vrn;
            }
        }
        short8 o;
        #pragma unroll
        for (int q = 0; q < 8; ++q) o[q] = (short)f2b(acc[q]);
        *((short8*)(accb + (size_t)head * EMBED) + lane) = o;
        if (lane == 0) { mh[head] = m; lh[head] = l; }
    }
    // block max: wave shfl_xor reduce + 4-slot LDS + one barrier
    __shared__ float wmax[4];
    float wm = mt;
    #pragma unroll
    for (int off = 1; off < 64; off <<= 1) wm = fmaxf(wm, __shfl_xor(wm, off, 64));
    if ((tid & 63) == 0) wmax[tid >> 6] = wm;
    __syncthreads();
    if (tid == 0)
        blockmax[blockIdx.x] = fmaxf(fmaxf(wmax[0], wmax[1]), fmaxf(wmax[2], wmax[3]));
}

// ---------------- K3b: reduce blockmax -> M ----------------
__global__ __launch_bounds__(256) void k_maxred(
    const float* __restrict__ blockmax, float* __restrict__ Mout, int n)
{
    __shared__ float smax[256];
    float m = -INFINITY;
    for (int i = threadIdx.x; i < n; i += 256) m = fmaxf(m, blockmax[i]);
    smax[threadIdx.x] = m;
    __syncthreads();
    for (int off = 128; off > 0; off >>= 1) {
        if ((int)threadIdx.x < off)
            smax[threadIdx.x] = fmaxf(smax[threadIdx.x], smax[threadIdx.x + off]);
        __syncthreads();
    }
    if (threadIdx.x == 0) Mout[0] = smax[0];
}

// ---------------- K4: fused normalize + x = ent + agg + bf16 MFMA GEMM ----------------
__global__ __launch_bounds__(256) void k_gemm_f(
    const short* __restrict__ entb, const short* __restrict__ accb,
    const float* __restrict__ mh, const float* __restrict__ lh,
    const float* __restrict__ Mptr, const short* __restrict__ wb,
    float* __restrict__ out, int N)
{
    __shared__ short xs[128 * LDSPAD];
    __shared__ short ws[128 * LDSPAD];
    __shared__ float invs[128];
    const int tid = threadIdx.x;
    const int n0  = blockIdx.x * 128;
    const float M = Mptr[0];

    if (tid < 128) {
        int g = n0 + tid;
        invs[tid] = (g < N) ? 1.0f / (lh[g] + 1e-10f * __expf(M - mh[g])) : 0.f;  // inf -> 0
    }
    // stage W (pre-cast bf16): 2048 short8 chunks, 8 per thread
    #pragma unroll
    for (int it = 0; it < 8; ++it) {
        int ch = it * 256 + tid;
        int row = ch >> 4, col8 = ch & 15;
        *(short8*)(ws + row * LDSPAD + col8 * 8) = ((const short8*)wb)[ch];
    }
    __syncthreads();
    // stage x = ent + acc*inv: 2048 short8 chunks, 8 per thread
    #pragma unroll
    for (int it = 0; it < 8; ++it) {
        int ch = it * 256 + tid;
        int row = ch >> 4, col8 = ch & 15;
        int g = n0 + row;
        short8 v = {0,0,0,0,0,0,0,0};
        if (g < N) {
            float inv = invs[row];
            short8 e8 = *((const short8*)(entb + (size_t)g * EMBED) + col8);
            short8 a8 = *((const short8*)(accb + (size_t)g * EMBED) + col8);
            #pragma unroll
            for (int q = 0; q < 8; ++q)
                v[q] = (short)f2b(b2f(e8[q]) + b2f(a8[q]) * inv);
        }
        *(short8*)(xs + row * LDSPAD + col8 * 8) = v;
    }
    __syncthreads();

    const int wv   = tid >> 6;
    const int lane = tid & 63;
    const int n16  = lane & 15;
    const int quad = lane >> 4;

    floatx4 acc[2][8];
    #pragma unroll
    for (int rt = 0; rt < 2; ++rt)
        #pragma unroll
        for (int jt = 0; jt < 8; ++jt)
            acc[rt][jt] = (floatx4){0.f, 0.f, 0.f, 0.f};

    #pragma unroll
    for (int kc = 0; kc < 4; ++kc) {
        int koff = kc * 32 + quad * 8;
        short8 a0 = *(const short8*)(xs + (wv * 32      + n16) * LDSPAD + koff);
        short8 a1 = *(const short8*)(xs + (wv * 32 + 16 + n16) * LDSPAD + koff);
        #pragma unroll
        for (int jt = 0; jt < 8; ++jt) {
            short8 b = *(const short8*)(ws + (jt * 16 + n16) * LDSPAD + koff);
            acc[0][jt] = __builtin_amdgcn_mfma_f32_16x16x32_bf16(a0, b, acc[0][jt], 0, 0, 0);
            acc[1][jt] = __builtin_amdgcn_mfma_f32_16x16x32_bf16(a1, b, acc[1][jt], 0, 0, 0);
        }
    }

    #pragma unroll
    for (int rt = 0; rt < 2; ++rt) {
        int rowbase = n0 + wv * 32 + rt * 16 + quad * 4;
        #pragma unroll
        for (int r = 0; r < 4; ++r) {
            int grow = rowbase + r;
            if (grow < N) {
                float* o = out + (size_t)grow * EMBED + n16;
                #pragma unroll
                for (int jt = 0; jt < 8; ++jt) {
                    float v = acc[rt][jt][r];
                    o[jt * 16] = (v > 0.f) ? v : 0.2f * v;
                }
            }
        }
    }
}

extern "C" void kernel_launch(void* const* d_in, const int* in_sizes, int n_in,
                              void* d_out, int out_size, void* d_ws, size_t ws_size,
                              hipStream_t stream)
{
    const float* ent   = (const float*)d_in[0];   // entity_emb  [N,128] fp32
    const float* rel   = (const float*)d_in[1];   // rel_embed   [R,128] fp32
    const float* W     = (const float*)d_in[2];   // W           [128,128] fp32
    const int*   heads = (const int*)d_in[3];
    const int*   rels  = (const int*)d_in[4];
    const int*   tails = (const int*)d_in[5];
    const int E = in_sizes[3];
    const int N = in_sizes[0] / EMBED;
    const int R = in_sizes[1] / EMBED;
    float* out = (float*)d_out;

    // ws layout:
    // accb[N*128]s | mh[N]f | lh[N]f | trp[E]i | cnt[N]i | bincur[64]i | offs[N]i |
    // cursor[N]i | blockmax[BMAX]f | Mval[4]f | bsum[1024]i | ghist[64]i | order[N]i |
    // wb[16384]s | entb[N*128]s | relb[R*128]s
    short* accb     = (short*)d_ws;
    float* mh       = (float*)(accb + (size_t)N * EMBED);
    float* lh       = mh + N;
    int*   trp      = (int*)(lh + N);
    int*   cnt      = trp + E;
    int*   bincur   = cnt + N;                      // zeroed together with cnt
    int*   offs     = bincur + DBINS;
    int*   cursor   = offs + N;
    float* blockmax = (float*)(cursor + N);
    float* Mval     = blockmax + BMAX;
    int*   bsum     = (int*)(Mval + 4);             // 16 B slot keeps alignment
    int*   ghist    = bsum + 1024;
    int*   order    = ghist + DBINS;
    short* wb       = (short*)(order + N);          // 128*128 bf16 = 32 KB
    short* entb     = wb + 16384;
    short* relb     = entb + (size_t)N * EMBED;

    const int nb  = (N + 1023) >> 10;       // scan blocks (<= 256 assumed: N <= 262144)
    const int ngh = (N + 15) / 16;          // per-head group blocks

    hipMemsetAsync(cnt, 0, (size_t)(N + DBINS) * sizeof(int), stream);

    int ngE = N * EMBED / 8, ngR = R * EMBED / 8, ngW = EMBED * EMBED / 8;
    k_cast_hist<<<2048, 256, 0, stream>>>(ent, rel, W, entb, relb, wb, heads, cnt, ghist, ngE, ngR, ngW, E);
    k_scan1<<<nb, 1024, 0, stream>>>(cnt, offs, bsum, ghist, N);
    k_scan23<<<(N + 255) / 256, 256, 0, stream>>>(offs, bsum, cursor, cnt, ghist, bincur, order, N, nb);
    k_csr<<<(E + 255) / 256, 256, 0, stream>>>(heads, rels, tails, cursor, trp, E);
    k_fused<<<ngh, 256, 0, stream>>>(entb, relb, offs, cnt, trp, order, accb, mh, lh, blockmax, N, R);
    k_maxred<<<1, 256, 0, stream>>>(blockmax, Mval, ngh);
    k_gemm_f<<<(N + 127) / 128, 256, 0, stream>>>(entb, accb, mh, lh, Mval, wb, out, N);
}